// Round 5
// baseline (243.958 us; speedup 1.0000x reference)
//
#include <hip/hip_runtime.h>
#include <math.h>

#define C 128

typedef __attribute__((ext_vector_type(8))) short short8;     // 8 bf16 (4 VGPRs)
typedef __attribute__((ext_vector_type(4))) float f32x4;
typedef __attribute__((ext_vector_type(4))) unsigned int uint4v;
typedef unsigned short u16;
typedef unsigned long long u64;

static __device__ __forceinline__ u16 f2bf(float f) {
  unsigned int u = __builtin_bit_cast(unsigned int, f);
  unsigned int r = (u + 0x7fffu + ((u >> 16) & 1u)) >> 16;
  return (u16)r;
}

// ---------------------------------------------------------------------------
// K0: fused fp32->bf16 convert + row norms + packed-NN init.
// ---------------------------------------------------------------------------
__global__ __launch_bounds__(256) void prep_kernel(
    const float* __restrict__ emb, const float* __restrict__ bank,
    u16* __restrict__ Abf, u16* __restrict__ Bbf, float* __restrict__ anorm,
    float* __restrict__ bnorm, u64* __restrict__ packed, int N, int M) {
  const int tid = threadIdx.x;
  const int chunk = blockIdx.x * 256 + tid;
  const int total = (N + M) * (C / 8);
  if (chunk >= total) return;
  if (chunk < N) packed[chunk] = ~0ull;   // fresh sentinel every launch
  const int gr = chunk >> 4;              // 16 chunks per 128-elem row
  const int co = (chunk & 15) * 8;
  const float* src;
  u16* dst;
  float* ndst;
  int r;
  if (gr < N) { src = emb; dst = Abf; ndst = anorm; r = gr; }
  else { src = bank; dst = Bbf; ndst = bnorm; r = gr - N; }
  const float* p = src + (size_t)r * C + co;
  float4 v0 = *(const float4*)p;
  float4 v1 = *(const float4*)(p + 4);
  u16 o[8] = {f2bf(v0.x), f2bf(v0.y), f2bf(v0.z), f2bf(v0.w),
              f2bf(v1.x), f2bf(v1.y), f2bf(v1.z), f2bf(v1.w)};
  *(uint4v*)(dst + (size_t)r * C + co) = *(const uint4v*)o;
  float s = v0.x * v0.x + v0.y * v0.y + v0.z * v0.z + v0.w * v0.w +
            v1.x * v1.x + v1.y * v1.y + v1.z * v1.z + v1.w * v1.w;
#pragma unroll
  for (int m = 1; m <= 8; m <<= 1) s += __shfl_xor(s, m, 64);
  if ((tid & 15) == 0) ndst[r] = s;
}

// ---------------------------------------------------------------------------
// K1 helpers
// ---------------------------------------------------------------------------
template <int K>
__device__ __forceinline__ void mfma16(const short8 af[4][4],
                                       const short8 bf[4], f32x4 acc[4][4]) {
#pragma unroll
  for (int fi = 0; fi < 4; ++fi)
#pragma unroll
    for (int fj = 0; fj < 4; ++fj)
      acc[fi][fj] = __builtin_amdgcn_mfma_f32_16x16x32_bf16(
          af[fi][K], bf[fj], acc[fi][fj], 0, 0, 0);
}

__device__ __forceinline__ void loadB(const u16* __restrict__ pb, int j0,
                                      int k, short8 bf[4]) {
#pragma unroll
  for (int fj = 0; fj < 4; ++fj)
    bf[fj] = *(const short8*)(pb + (size_t)(j0 + fj * 16) * C + k * 32);
}

// ---------------------------------------------------------------------------
// K1: barrier-free MFMA NN search.  grid 784 (=98 row-tiles x 8 bank-eighths,
// decoded XCD-first so each bank eighth stays in one XCD's L2).  4 waves in
// 2x2; each wave: 64 rows x 64 cols per tile, B streamed global->reg with a
// 1-tile ping-pong, A fragments register-resident.  Result merged globally
// via atomicMin on packed (d2_bits<<32 | bank_idx).
// ---------------------------------------------------------------------------
__global__ __launch_bounds__(256, 2) void nn_mfma(
    const u16* __restrict__ Abf, const u16* __restrict__ Bbf,
    const float* __restrict__ bnorm, const float* __restrict__ anorm,
    u64* __restrict__ packed, int N, int M) {
  const int tid = threadIdx.x;
  const int lane = tid & 63;
  const int w = tid >> 6;
  const int wr = w >> 1, wc = w & 1;     // 2x2 wave grid
  const int lr = lane & 15, kg = lane >> 4;
  const int bid = blockIdx.x;
  const int ychunk = bid & 7;            // XCD-aligned bank eighth
  const int row0 = (bid >> 3) * 128;
  const int jchunk = M >> 3;             // 2048
  const int j0base = ychunk * jchunk;

  // A fragments straight from global (once)
  short8 af[4][4];
  {
    const u16* pa = Abf + (size_t)(row0 + wr * 64 + lr) * C + kg * 8;
#pragma unroll
    for (int fi = 0; fi < 4; ++fi)
#pragma unroll
      for (int k = 0; k < 4; ++k)
        af[fi][k] = *(const short8*)(pa + fi * 16 * C + k * 32);
  }

  float minv[16];
  int mini[16];
#pragma unroll
  for (int s = 0; s < 16; ++s) { minv[s] = INFINITY; mini[s] = 0x7fffffff; }

  const u16* pb = Bbf + (size_t)(wc * 64 + lr) * C + kg * 8;
  short8 b0[4], b1[4];
  float bnc[4], bnn[4];
  int j0 = j0base;
  loadB(pb, j0, 0, b0);
#pragma unroll
  for (int fj = 0; fj < 4; ++fj) bnc[fj] = bnorm[j0 + wc * 64 + fj * 16 + lr];

  for (int t = 0; t < 16; ++t) {
    const int jn = (t == 15) ? j0base : j0 + 128;
    f32x4 acc[4][4];
#pragma unroll
    for (int fi = 0; fi < 4; ++fi)
#pragma unroll
      for (int fj = 0; fj < 4; ++fj) {
        f32x4 z = {0.0f, 0.0f, 0.0f, 0.0f};
        acc[fi][fj] = z;
      }

    loadB(pb, j0, 1, b1);
    mfma16<0>(af, b0, acc);
    loadB(pb, j0, 2, b0);
    mfma16<1>(af, b1, acc);
    loadB(pb, j0, 3, b1);
    mfma16<2>(af, b0, acc);
    loadB(pb, jn, 0, b0);
#pragma unroll
    for (int fj = 0; fj < 4; ++fj)
      bnn[fj] = bnorm[jn + wc * 64 + fj * 16 + lr];
    mfma16<3>(af, b1, acc);

    // min-epilogue: v = bnorm[col] - 2*dot; C/D: col=lane&15, row=kg*4+reg
#pragma unroll
    for (int fj = 0; fj < 4; ++fj) {
      const int col = j0 + wc * 64 + fj * 16 + lr;
      const float bn = bnc[fj];
#pragma unroll
      for (int fi = 0; fi < 4; ++fi) {
#pragma unroll
        for (int r = 0; r < 4; ++r) {
          float v = fmaf(-2.0f, acc[fi][fj][r], bn);
          const int s = fi * 4 + r;
          if (v < minv[s]) { minv[s] = v; mini[s] = col; }
        }
      }
    }
#pragma unroll
    for (int fj = 0; fj < 4; ++fj) bnc[fj] = bnn[fj];
    j0 = jn;
  }

  // butterfly min over the 16 col-classes (lane bits 0..3), then global merge
#pragma unroll
  for (int s = 0; s < 16; ++s) {
    float v = minv[s];
    int ix = mini[s];
#pragma unroll
    for (int m = 1; m <= 8; m <<= 1) {
      float ov = __shfl_xor(v, m, 64);
      int oi = __shfl_xor(ix, m, 64);
      if (ov < v || (ov == v && oi < ix)) { v = ov; ix = oi; }
    }
    if (lr == 0) {
      const int row = row0 + wr * 64 + (s >> 2) * 16 + kg * 4 + (s & 3);
      float d2 = fmaxf(anorm[row] + v, 0.0f);
      u64 pk = ((u64)__float_as_uint(d2) << 32) | (unsigned)ix;
      atomicMin(&packed[row], pk);
    }
  }
}

// ---------------------------------------------------------------------------
// K2: per-image argmax over packed d2 (first occurrence) -> score/nnidx/maxrow
// ---------------------------------------------------------------------------
__global__ __launch_bounds__(256) void batch_argmax(
    const u64* __restrict__ packed, float* __restrict__ score,
    int* __restrict__ nnidx, int* __restrict__ maxrow) {
  const int b = blockIdx.x;
  __shared__ float sv[256];
  __shared__ int si[256];
  __shared__ int sl[256];
  const int tid = threadIdx.x;
  float bv = -INFINITY;
  int bi_ = 0x7fffffff, bl = 0;
  for (int i = tid; i < 784; i += 256) {
    u64 p = packed[(size_t)b * 784 + i];
    float v = __uint_as_float((unsigned)(p >> 32));
    if (v > bv) { bv = v; bi_ = i; bl = (int)(unsigned)p; }
  }
  sv[tid] = bv; si[tid] = bi_; sl[tid] = bl;
  __syncthreads();
  for (int s = 128; s > 0; s >>= 1) {
    if (tid < s) {
      if (sv[tid + s] > sv[tid] ||
          (sv[tid + s] == sv[tid] && si[tid + s] < si[tid])) {
        sv[tid] = sv[tid + s]; si[tid] = si[tid + s]; sl[tid] = sl[tid + s];
      }
    }
    __syncthreads();
  }
  if (tid == 0) {
    score[b] = sqrtf(fmaxf(sv[0], 1e-12f));
    maxrow[b] = b * 784 + si[0];
    nnidx[b] = sl[0];
  }
}

// ---------------------------------------------------------------------------
// K3a: per-(image, bank-chunk) top-9 candidates.  grid (16, B), block 256.
// ---------------------------------------------------------------------------
__global__ __launch_bounds__(256) void rescore_part(
    const float* __restrict__ Bk, const float* __restrict__ bnorm,
    const int* __restrict__ nnidx, float* __restrict__ cvals,
    int* __restrict__ cidx, int M) {
  const int c = blockIdx.x;   // chunk
  const int b = blockIdx.y;   // image
  const int tid = threadIdx.x;
  __shared__ float vec[C];
  __shared__ float sv[256];
  __shared__ int si[256];
  const int nn = nnidx[b];
  if (tid < 32)
    *(float4*)&vec[tid * 4] = *(const float4*)(Bk + (size_t)nn * C + tid * 4);
  __syncthreads();
  const float nnorm = bnorm[nn];
  const int j0 = c * (M >> 4);
  float rv[4];
  int rj[4];
#pragma unroll
  for (int q = 0; q < 4; ++q) {
    const int j = j0 + q * 256 + tid;
    const float4* br = (const float4*)(Bk + (size_t)j * C);
    float dot = 0.0f;
#pragma unroll
    for (int kc = 0; kc < 32; ++kc) {
      float4 v = br[kc];
      float4 ww = *(const float4*)&vec[kc * 4];
      dot += v.x * ww.x + v.y * ww.y + v.z * ww.z + v.w * ww.w;
    }
    rv[q] = nnorm + bnorm[j] - 2.0f * dot;
    rj[q] = j;
  }
  for (int s9 = 0; s9 < 9; ++s9) {
    float bv = INFINITY;
    int bj = 0x7fffffff;
#pragma unroll
    for (int q = 0; q < 4; ++q)
      if (rv[q] < bv) { bv = rv[q]; bj = rj[q]; }  // ascending j keeps first
    sv[tid] = bv; si[tid] = bj;
    __syncthreads();
    for (int s = 128; s > 0; s >>= 1) {
      if (tid < s) {
        if (sv[tid + s] < sv[tid] ||
            (sv[tid + s] == sv[tid] && si[tid + s] < si[tid])) {
          sv[tid] = sv[tid + s]; si[tid] = si[tid + s];
        }
      }
      __syncthreads();
    }
    const int selj = si[0];
    if (tid == 0) {
      cvals[((size_t)b * 16 + c) * 9 + s9] = sv[0];
      cidx[((size_t)b * 16 + c) * 9 + s9] = selj;
    }
#pragma unroll
    for (int q = 0; q < 4; ++q)
      if (rj[q] == selj) rv[q] = INFINITY;
    __syncthreads();
  }
}

// ---------------------------------------------------------------------------
// K3b: merge 144 candidates -> exact top-9, support distances, softmax.
// grid B, block 256 (4 waves).
// ---------------------------------------------------------------------------
__global__ __launch_bounds__(256) void rescore_merge(
    const float* __restrict__ emb, const float* __restrict__ Bk,
    const float* __restrict__ cvals, const int* __restrict__ cidx,
    const float* __restrict__ score, const int* __restrict__ maxrow,
    float* __restrict__ pred) {
  const int b = blockIdx.x;
  const int tid = threadIdx.x;
  const int w = tid >> 6, lane = tid & 63;
  __shared__ float wv[144];
  __shared__ int wi[144];
  __shared__ float sv[256];
  __shared__ int si[256];
  __shared__ int sp[256];
  __shared__ int sup[9];
  __shared__ float vec[C];
  __shared__ float ds[9];
  if (tid < 144) {
    wv[tid] = cvals[(size_t)b * 144 + tid];
    wi[tid] = cidx[(size_t)b * 144 + tid];
  }
  if (tid < 32)
    *(float4*)&vec[tid * 4] =
        *(const float4*)(emb + (size_t)maxrow[b] * C + tid * 4);
  __syncthreads();
  for (int s9 = 0; s9 < 9; ++s9) {
    if (tid < 144) { sv[tid] = wv[tid]; si[tid] = wi[tid]; sp[tid] = tid; }
    else { sv[tid] = INFINITY; si[tid] = 0x7fffffff; sp[tid] = -1; }
    __syncthreads();
    for (int s = 128; s > 0; s >>= 1) {
      if (tid < s) {
        if (sv[tid + s] < sv[tid] ||
            (sv[tid + s] == sv[tid] && si[tid + s] < si[tid])) {
          sv[tid] = sv[tid + s]; si[tid] = si[tid + s]; sp[tid] = sp[tid + s];
        }
      }
      __syncthreads();
    }
    if (tid == 0) {
      sup[s9] = si[0];
      wv[sp[0]] = INFINITY;
    }
    __syncthreads();
  }
  // support distances: wave w handles supports s = w, w+4, ...
  for (int s = w; s < 9; s += 4) {
    const float* br = Bk + (size_t)sup[s] * C;
    float d0 = vec[lane * 2] - br[lane * 2];
    float d1 = vec[lane * 2 + 1] - br[lane * 2 + 1];
    float acc = d0 * d0 + d1 * d1;
#pragma unroll
    for (int m = 1; m <= 32; m <<= 1) acc += __shfl_xor(acc, m, 64);
    if (lane == 0) ds[s] = sqrtf(fmaxf(acc, 1e-12f));
  }
  __syncthreads();
  if (tid == 0) {
    float m = ds[0];
    for (int t = 1; t < 9; ++t) m = fmaxf(m, ds[t]);
    float sum = 0.0f, e0 = 0.0f;
    for (int t = 0; t < 9; ++t) {
      float e = expf(ds[t] - m);
      sum += e;
      if (t == 0) e0 = e;
    }
    pred[b] = (1.0f - e0 / sum) * score[b];
  }
}

// ---------------------------------------------------------------------------
// K4: fused upsample+blur.  Vertical 33 taps collapse to <=6 coarse-row
// weights (tmp rows within an octet are identical), so one kernel and no
// 3.2MB tmp.  grid (224, B), 256 threads; sqrt(d2) read from packed.
// ---------------------------------------------------------------------------
__global__ __launch_bounds__(256) void blur_fused(
    const u64* __restrict__ packed, float* __restrict__ out) {
  const int y = blockIdx.x, b = blockIdx.y;
  const int tid = threadIdx.x;
  __shared__ float g[33];
  __shared__ float rows[6][28];
  if (tid < 33) {
    float d = (float)tid - 16.0f;
    g[tid] = expf(-(d * d) * (1.0f / 32.0f));
  }
  // vertical coarse-row window (uniform in y)
  int rcmin = 27;
  for (int t = 0; t < 33; ++t) {
    int yy = y + t - 16;
    yy = yy < 0 ? -yy : (yy > 223 ? 446 - yy : yy);
    int rc = yy >> 3;
    rcmin = rc < rcmin ? rc : rcmin;
  }
  if (tid < 168) {
    const int i = tid / 28, cc = tid - i * 28;
    int rc = rcmin + i;
    rc = rc > 27 ? 27 : rc;
    u64 p = packed[(size_t)b * 784 + rc * 28 + cc];
    float d2 = __uint_as_float((unsigned)(p >> 32));
    rows[i][cc] = sqrtf(fmaxf(d2, 1e-12f));
  }
  __syncthreads();
  float gv[6];
#pragma unroll
  for (int i = 0; i < 6; ++i) gv[i] = 0.0f;
  for (int t = 0; t < 33; ++t) {
    int yy = y + t - 16;
    yy = yy < 0 ? -yy : (yy > 223 ? 446 - yy : yy);
    const int idx = (yy >> 3) - rcmin;
    const float gt = g[t];
#pragma unroll
    for (int i = 0; i < 6; ++i) gv[i] += (idx == i) ? gt : 0.0f;
  }
  if (tid < 224) {
    float hacc[6];
#pragma unroll
    for (int i = 0; i < 6; ++i) hacc[i] = 0.0f;
    for (int s = 0; s < 33; ++s) {
      int xx = tid + s - 16;
      xx = xx < 0 ? -xx : (xx > 223 ? 446 - xx : xx);
      const int cs = xx >> 3;
      const float gs_ = g[s];
#pragma unroll
      for (int i = 0; i < 6; ++i) hacc[i] += gs_ * rows[i][cs];
    }
    float acc = 0.0f, gsum = 0.0f;
#pragma unroll
    for (int i = 0; i < 6; ++i) { acc += gv[i] * hacc[i]; gsum += gv[i]; }
    out[((size_t)b * 224 + y) * 224 + tid] = acc / (gsum * gsum);
  }
}

// ---------------------------------------------------------------------------
extern "C" void kernel_launch(void* const* d_in, const int* in_sizes, int n_in,
                              void* d_out, int out_size, void* d_ws,
                              size_t ws_size, hipStream_t stream) {
  const float* emb = (const float*)d_in[0];
  const float* bank = (const float*)d_in[1];
  const int N = in_sizes[0] / C;  // 12544
  const int M = in_sizes[1] / C;  // 16384
  const int B = 16;

  u16* Abf = (u16*)d_ws;                          // N*C bf16
  u16* Bbf = Abf + (size_t)N * C;                 // M*C bf16
  u64* packed = (u64*)(Bbf + (size_t)M * C);      // N   (8B-aligned)
  float* anorm = (float*)(packed + N);            // N
  float* bnorm = anorm + N;                       // M
  float* score = bnorm + M;                       // B
  int* nnidx = (int*)(score + B);                 // B
  int* maxrow = nnidx + B;                        // B
  float* cvals = (float*)(maxrow + B);            // B*144
  int* cidx = (int*)(cvals + B * 144);            // B*144

  float* out_map = (float*)d_out;
  float* out_pred = out_map + (size_t)B * 224 * 224;

  const int total = (N + M) * (C / 8);
  prep_kernel<<<(total + 255) / 256, 256, 0, stream>>>(emb, bank, Abf, Bbf,
                                                       anorm, bnorm, packed,
                                                       N, M);
  nn_mfma<<<(N / 128) * 8, 256, 0, stream>>>(Abf, Bbf, bnorm, anorm, packed,
                                             N, M);
  batch_argmax<<<B, 256, 0, stream>>>(packed, score, nnidx, maxrow);
  rescore_part<<<dim3(16, B), 256, 0, stream>>>(bank, bnorm, nnidx, cvals,
                                                cidx, M);
  rescore_merge<<<B, 256, 0, stream>>>(emb, bank, cvals, cidx, score, maxrow,
                                       out_pred);
  blur_fused<<<dim3(224, B), 256, 0, stream>>>(packed, out_map);
}

// Round 6
// 187.140 us; speedup vs baseline: 1.3036x; 1.3036x over previous
//
#include <hip/hip_runtime.h>
#include <math.h>

#define C 128

typedef __attribute__((ext_vector_type(8))) short short8;     // 8 bf16 (4 VGPRs)
typedef __attribute__((ext_vector_type(4))) float f32x4;
typedef __attribute__((ext_vector_type(4))) unsigned int uint4v;
typedef unsigned short u16;
typedef unsigned long long u64;

static __device__ __forceinline__ u16 f2bf(float f) {
  unsigned int u = __builtin_bit_cast(unsigned int, f);
  unsigned int r = (u + 0x7fffu + ((u >> 16) & 1u)) >> 16;
  return (u16)r;
}

// async global->LDS, 16B per lane; LDS dest = wave-uniform base + lane*16
static __device__ __forceinline__ void gload_lds16(const void* g, void* l) {
  __builtin_amdgcn_global_load_lds(
      (const __attribute__((address_space(1))) unsigned int*)g,
      (__attribute__((address_space(3))) unsigned int*)l, 16, 0, 0);
}

// ---------------------------------------------------------------------------
// K0: fused fp32->bf16 convert + row norms + packed-NN init.
// ---------------------------------------------------------------------------
__global__ __launch_bounds__(256) void prep_kernel(
    const float* __restrict__ emb, const float* __restrict__ bank,
    u16* __restrict__ Abf, u16* __restrict__ Bbf, float* __restrict__ anorm,
    float* __restrict__ bnorm, u64* __restrict__ packed, int N, int M) {
  const int tid = threadIdx.x;
  const int chunk = blockIdx.x * 256 + tid;
  const int total = (N + M) * (C / 8);
  if (chunk >= total) return;
  if (chunk < N) packed[chunk] = ~0ull;   // fresh sentinel every launch
  const int gr = chunk >> 4;              // 16 chunks per 128-elem row
  const int co = (chunk & 15) * 8;
  const float* src;
  u16* dst;
  float* ndst;
  int r;
  if (gr < N) { src = emb; dst = Abf; ndst = anorm; r = gr; }
  else { src = bank; dst = Bbf; ndst = bnorm; r = gr - N; }
  const float* p = src + (size_t)r * C + co;
  float4 v0 = *(const float4*)p;
  float4 v1 = *(const float4*)(p + 4);
  u16 o[8] = {f2bf(v0.x), f2bf(v0.y), f2bf(v0.z), f2bf(v0.w),
              f2bf(v1.x), f2bf(v1.y), f2bf(v1.z), f2bf(v1.w)};
  *(uint4v*)(dst + (size_t)r * C + co) = *(const uint4v*)o;
  float s = v0.x * v0.x + v0.y * v0.y + v0.z * v0.z + v0.w * v0.w +
            v1.x * v1.x + v1.y * v1.y + v1.z * v1.z + v1.w * v1.w;
#pragma unroll
  for (int m = 1; m <= 8; m <<= 1) s += __shfl_xor(s, m, 64);
  if ((tid & 15) == 0) ndst[r] = s;
}

// ---------------------------------------------------------------------------
// K1 helper: 16 MFMAs for one K-step
// ---------------------------------------------------------------------------
template <int K>
__device__ __forceinline__ void mfma16(const short8 af[4][4],
                                       const short8 bf[4], f32x4 acc[4][4]) {
#pragma unroll
  for (int fi = 0; fi < 4; ++fi)
#pragma unroll
    for (int fj = 0; fj < 4; ++fj)
      acc[fi][fj] = __builtin_amdgcn_mfma_f32_16x16x32_bf16(
          af[fi][K], bf[fj], acc[fi][fj], 0, 0, 0);
}

// ---------------------------------------------------------------------------
// K1: MFMA NN search, m97-structure.  grid 784 = 98 row-tiles x 8 bank-
// eighths (XCD-first decode: ychunk == XCD id -> each XCD L2 holds only its
// 512KB bank slice + 3MB A slice).  A fragments register-resident (K=128).
// B-tiles (128x128 bf16 = 32KB) double-buffered in LDS via global_load_lds
// width 16 with BOTH-SIDES XOR swizzle (rule #21): linear LDS dest, inverse-
// swizzled global source, swizzled ds_read -> conflict-free b128 reads.
// One barrier per tile; prefetch issued before compute (loads fly under
// MFMA, drained by the pre-barrier vmcnt(0)).
// Global merge via atomicMin on packed (d2_bits<<32 | bank_idx).
// ---------------------------------------------------------------------------
__global__ __launch_bounds__(256, 2) void nn_mfma(
    const u16* __restrict__ Abf, const u16* __restrict__ Bbf,
    const float* __restrict__ bnorm, const float* __restrict__ anorm,
    u64* __restrict__ packed, int N, int M) {
  __shared__ short Bs[2][16384];       // 2 x 32KB
  const int tid = threadIdx.x;
  const int lane = tid & 63;
  const int w = tid >> 6;
  const int wr = w >> 1, wc = w & 1;   // 2x2 wave grid
  const int lr = lane & 15, kg = lane >> 4;
  const int bid = blockIdx.x;
  const int ychunk = bid & 7;          // == XCD id
  const int row0 = (bid >> 3) * 128;
  const int j0base = ychunk * (M >> 3);

  // per-lane inverse-swizzled source offsets for the 8 stage issues.
  // LDS byte o = q*4096 + tid*16 ; r = o>>8 ; c2 = (o&255) ^ ((r&7)<<4)
  int soff[8];
#pragma unroll
  for (int q = 0; q < 8; ++q) {
    const int r = q * 16 + (tid >> 4);
    const int c = (((tid & 15) * 16) ^ ((r & 7) << 4)) >> 1;
    soff[q] = r * C + c;
  }

#define STAGE(bufi, jj)                                                     \
  do {                                                                      \
    const u16* gsrc = Bbf + (size_t)(jj) * C;                               \
    _Pragma("unroll") for (int q = 0; q < 8; ++q)                           \
        gload_lds16(gsrc + soff[q], &Bs[bufi][q * 2048 + w * 512]);         \
  } while (0)

  // A fragments straight from global (once; L2/L3-resident)
  short8 af[4][4];
  {
    const u16* pa = Abf + (size_t)(row0 + wr * 64 + lr) * C + kg * 8;
#pragma unroll
    for (int fi = 0; fi < 4; ++fi)
#pragma unroll
      for (int k = 0; k < 4; ++k)
        af[fi][k] = *(const short8*)(pa + fi * 16 * C + k * 32);
  }

  float minv[16];
  int mini[16];
#pragma unroll
  for (int s = 0; s < 16; ++s) { minv[s] = INFINITY; mini[s] = 0x7fffffff; }

  STAGE(0, j0base);
  __syncthreads();                     // tile 0 resident

  int j0 = j0base;
  for (int t = 0; t < 16; ++t) {
    const int buf = t & 1;
    if (t < 15) STAGE(buf ^ 1, j0 + 128);   // async; flies under compute

    float bnc[4];
#pragma unroll
    for (int fj = 0; fj < 4; ++fj)
      bnc[fj] = bnorm[j0 + wc * 64 + fj * 16 + lr];

    f32x4 acc[4][4];
#pragma unroll
    for (int fi = 0; fi < 4; ++fi)
#pragma unroll
      for (int fj = 0; fj < 4; ++fj) {
        f32x4 z = {0.0f, 0.0f, 0.0f, 0.0f};
        acc[fi][fj] = z;
      }

    const short* bsb = &Bs[buf][0];
    const int cxor = (lr & 7) << 3;    // short-index XOR = byte XOR <<4
#define LDB(kk)                                                            \
    {                                                                      \
      short8 bf[4];                                                        \
      _Pragma("unroll") for (int fj = 0; fj < 4; ++fj) {                   \
        const int row = wc * 64 + fj * 16 + lr;                            \
        bf[fj] = *(const short8*)&bsb[row * C + ((kk * 32 + kg * 8) ^ cxor)]; \
      }                                                                    \
      mfma16<kk>(af, bf, acc);                                             \
    }
    LDB(0) LDB(1) LDB(2) LDB(3)
#undef LDB

    // min-epilogue: v = bnorm[col] - 2*dot; C/D: col=lane&15, row=kg*4+reg
#pragma unroll
    for (int fj = 0; fj < 4; ++fj) {
      const int col = j0 + wc * 64 + fj * 16 + lr;
      const float bn = bnc[fj];
#pragma unroll
      for (int fi = 0; fi < 4; ++fi) {
#pragma unroll
        for (int r = 0; r < 4; ++r) {
          float v = fmaf(-2.0f, acc[fi][fj][r], bn);
          const int s = fi * 4 + r;
          if (v < minv[s]) { minv[s] = v; mini[s] = col; }
        }
      }
    }
    __syncthreads();   // all waves done with buf; prefetch (t+1) arrived
    j0 += 128;
  }
#undef STAGE

  // butterfly min over the 16 col-classes (lane bits 0..3), then global merge
#pragma unroll
  for (int s = 0; s < 16; ++s) {
    float v = minv[s];
    int ix = mini[s];
#pragma unroll
    for (int m = 1; m <= 8; m <<= 1) {
      float ov = __shfl_xor(v, m, 64);
      int oi = __shfl_xor(ix, m, 64);
      if (ov < v || (ov == v && oi < ix)) { v = ov; ix = oi; }
    }
    if (lr == 0) {
      const int row = row0 + wr * 64 + (s >> 2) * 16 + kg * 4 + (s & 3);
      float d2 = fmaxf(anorm[row] + v, 0.0f);
      u64 pk = ((u64)__float_as_uint(d2) << 32) | (unsigned)ix;
      atomicMin(&packed[row], pk);
    }
  }
}

// ---------------------------------------------------------------------------
// K2: per-image argmax over packed d2 (first occurrence) -> score/nnidx/maxrow
// ---------------------------------------------------------------------------
__global__ __launch_bounds__(256) void batch_argmax(
    const u64* __restrict__ packed, float* __restrict__ score,
    int* __restrict__ nnidx, int* __restrict__ maxrow) {
  const int b = blockIdx.x;
  __shared__ float sv[256];
  __shared__ int si[256];
  __shared__ int sl[256];
  const int tid = threadIdx.x;
  float bv = -INFINITY;
  int bi_ = 0x7fffffff, bl = 0;
  for (int i = tid; i < 784; i += 256) {
    u64 p = packed[(size_t)b * 784 + i];
    float v = __uint_as_float((unsigned)(p >> 32));
    if (v > bv) { bv = v; bi_ = i; bl = (int)(unsigned)p; }
  }
  sv[tid] = bv; si[tid] = bi_; sl[tid] = bl;
  __syncthreads();
  for (int s = 128; s > 0; s >>= 1) {
    if (tid < s) {
      if (sv[tid + s] > sv[tid] ||
          (sv[tid + s] == sv[tid] && si[tid + s] < si[tid])) {
        sv[tid] = sv[tid + s]; si[tid] = si[tid + s]; sl[tid] = sl[tid + s];
      }
    }
    __syncthreads();
  }
  if (tid == 0) {
    score[b] = sqrtf(fmaxf(sv[0], 1e-12f));
    maxrow[b] = b * 784 + si[0];
    nnidx[b] = sl[0];
  }
}

// ---------------------------------------------------------------------------
// K3a: per-(image, bank-chunk) top-9 candidates.  grid (16, B), block 256.
// ---------------------------------------------------------------------------
__global__ __launch_bounds__(256) void rescore_part(
    const float* __restrict__ Bk, const float* __restrict__ bnorm,
    const int* __restrict__ nnidx, float* __restrict__ cvals,
    int* __restrict__ cidx, int M) {
  const int c = blockIdx.x;   // chunk
  const int b = blockIdx.y;   // image
  const int tid = threadIdx.x;
  __shared__ float vec[C];
  __shared__ float sv[256];
  __shared__ int si[256];
  const int nn = nnidx[b];
  if (tid < 32)
    *(float4*)&vec[tid * 4] = *(const float4*)(Bk + (size_t)nn * C + tid * 4);
  __syncthreads();
  const float nnorm = bnorm[nn];
  const int j0 = c * (M >> 4);
  float rv[4];
  int rj[4];
#pragma unroll
  for (int q = 0; q < 4; ++q) {
    const int j = j0 + q * 256 + tid;
    const float4* br = (const float4*)(Bk + (size_t)j * C);
    float dot = 0.0f;
#pragma unroll
    for (int kc = 0; kc < 32; ++kc) {
      float4 v = br[kc];
      float4 ww = *(const float4*)&vec[kc * 4];
      dot += v.x * ww.x + v.y * ww.y + v.z * ww.z + v.w * ww.w;
    }
    rv[q] = nnorm + bnorm[j] - 2.0f * dot;
    rj[q] = j;
  }
  for (int s9 = 0; s9 < 9; ++s9) {
    float bv = INFINITY;
    int bj = 0x7fffffff;
#pragma unroll
    for (int q = 0; q < 4; ++q)
      if (rv[q] < bv) { bv = rv[q]; bj = rj[q]; }  // ascending j keeps first
    sv[tid] = bv; si[tid] = bj;
    __syncthreads();
    for (int s = 128; s > 0; s >>= 1) {
      if (tid < s) {
        if (sv[tid + s] < sv[tid] ||
            (sv[tid + s] == sv[tid] && si[tid + s] < si[tid])) {
          sv[tid] = sv[tid + s]; si[tid] = si[tid + s];
        }
      }
      __syncthreads();
    }
    const int selj = si[0];
    if (tid == 0) {
      cvals[((size_t)b * 16 + c) * 9 + s9] = sv[0];
      cidx[((size_t)b * 16 + c) * 9 + s9] = selj;
    }
#pragma unroll
    for (int q = 0; q < 4; ++q)
      if (rj[q] == selj) rv[q] = INFINITY;
    __syncthreads();
  }
}

// ---------------------------------------------------------------------------
// K3b: merge 144 candidates -> exact top-9, support distances, softmax.
// ---------------------------------------------------------------------------
__global__ __launch_bounds__(256) void rescore_merge(
    const float* __restrict__ emb, const float* __restrict__ Bk,
    const float* __restrict__ cvals, const int* __restrict__ cidx,
    const float* __restrict__ score, const int* __restrict__ maxrow,
    float* __restrict__ pred) {
  const int b = blockIdx.x;
  const int tid = threadIdx.x;
  const int w = tid >> 6, lane = tid & 63;
  __shared__ float wv[144];
  __shared__ int wi[144];
  __shared__ float sv[256];
  __shared__ int si[256];
  __shared__ int sp[256];
  __shared__ int sup[9];
  __shared__ float vec[C];
  __shared__ float ds[9];
  if (tid < 144) {
    wv[tid] = cvals[(size_t)b * 144 + tid];
    wi[tid] = cidx[(size_t)b * 144 + tid];
  }
  if (tid < 32)
    *(float4*)&vec[tid * 4] =
        *(const float4*)(emb + (size_t)maxrow[b] * C + tid * 4);
  __syncthreads();
  for (int s9 = 0; s9 < 9; ++s9) {
    if (tid < 144) { sv[tid] = wv[tid]; si[tid] = wi[tid]; sp[tid] = tid; }
    else { sv[tid] = INFINITY; si[tid] = 0x7fffffff; sp[tid] = -1; }
    __syncthreads();
    for (int s = 128; s > 0; s >>= 1) {
      if (tid < s) {
        if (sv[tid + s] < sv[tid] ||
            (sv[tid + s] == sv[tid] && si[tid + s] < si[tid])) {
          sv[tid] = sv[tid + s]; si[tid] = si[tid + s]; sp[tid] = sp[tid + s];
        }
      }
      __syncthreads();
    }
    if (tid == 0) {
      sup[s9] = si[0];
      wv[sp[0]] = INFINITY;
    }
    __syncthreads();
  }
  for (int s = w; s < 9; s += 4) {
    const float* br = Bk + (size_t)sup[s] * C;
    float d0 = vec[lane * 2] - br[lane * 2];
    float d1 = vec[lane * 2 + 1] - br[lane * 2 + 1];
    float acc = d0 * d0 + d1 * d1;
#pragma unroll
    for (int m = 1; m <= 32; m <<= 1) acc += __shfl_xor(acc, m, 64);
    if (lane == 0) ds[s] = sqrtf(fmaxf(acc, 1e-12f));
  }
  __syncthreads();
  if (tid == 0) {
    float m = ds[0];
    for (int t = 1; t < 9; ++t) m = fmaxf(m, ds[t]);
    float sum = 0.0f, e0 = 0.0f;
    for (int t = 0; t < 9; ++t) {
      float e = expf(ds[t] - m);
      sum += e;
      if (t == 0) e0 = e;
    }
    pred[b] = (1.0f - e0 / sum) * score[b];
  }
}

// ---------------------------------------------------------------------------
// K4: fused upsample+blur (vertical taps collapse to <=6 coarse-row weights)
// ---------------------------------------------------------------------------
__global__ __launch_bounds__(256) void blur_fused(
    const u64* __restrict__ packed, float* __restrict__ out) {
  const int y = blockIdx.x, b = blockIdx.y;
  const int tid = threadIdx.x;
  __shared__ float g[33];
  __shared__ float rows[6][28];
  if (tid < 33) {
    float d = (float)tid - 16.0f;
    g[tid] = expf(-(d * d) * (1.0f / 32.0f));
  }
  int rcmin = 27;
  for (int t = 0; t < 33; ++t) {
    int yy = y + t - 16;
    yy = yy < 0 ? -yy : (yy > 223 ? 446 - yy : yy);
    int rc = yy >> 3;
    rcmin = rc < rcmin ? rc : rcmin;
  }
  if (tid < 168) {
    const int i = tid / 28, cc = tid - i * 28;
    int rc = rcmin + i;
    rc = rc > 27 ? 27 : rc;
    u64 p = packed[(size_t)b * 784 + rc * 28 + cc];
    float d2 = __uint_as_float((unsigned)(p >> 32));
    rows[i][cc] = sqrtf(fmaxf(d2, 1e-12f));
  }
  __syncthreads();
  float gv[6];
#pragma unroll
  for (int i = 0; i < 6; ++i) gv[i] = 0.0f;
  for (int t = 0; t < 33; ++t) {
    int yy = y + t - 16;
    yy = yy < 0 ? -yy : (yy > 223 ? 446 - yy : yy);
    const int idx = (yy >> 3) - rcmin;
    const float gt = g[t];
#pragma unroll
    for (int i = 0; i < 6; ++i) gv[i] += (idx == i) ? gt : 0.0f;
  }
  if (tid < 224) {
    float hacc[6];
#pragma unroll
    for (int i = 0; i < 6; ++i) hacc[i] = 0.0f;
    for (int s = 0; s < 33; ++s) {
      int xx = tid + s - 16;
      xx = xx < 0 ? -xx : (xx > 223 ? 446 - xx : xx);
      const int cs = xx >> 3;
      const float gs_ = g[s];
#pragma unroll
      for (int i = 0; i < 6; ++i) hacc[i] += gs_ * rows[i][cs];
    }
    float acc = 0.0f, gsum = 0.0f;
#pragma unroll
    for (int i = 0; i < 6; ++i) { acc += gv[i] * hacc[i]; gsum += gv[i]; }
    out[((size_t)b * 224 + y) * 224 + tid] = acc / (gsum * gsum);
  }
}

// ---------------------------------------------------------------------------
extern "C" void kernel_launch(void* const* d_in, const int* in_sizes, int n_in,
                              void* d_out, int out_size, void* d_ws,
                              size_t ws_size, hipStream_t stream) {
  const float* emb = (const float*)d_in[0];
  const float* bank = (const float*)d_in[1];
  const int N = in_sizes[0] / C;  // 12544
  const int M = in_sizes[1] / C;  // 16384
  const int B = 16;

  u16* Abf = (u16*)d_ws;                          // N*C bf16
  u16* Bbf = Abf + (size_t)N * C;                 // M*C bf16
  u64* packed = (u64*)(Bbf + (size_t)M * C);      // N   (8B-aligned)
  float* anorm = (float*)(packed + N);            // N
  float* bnorm = anorm + N;                       // M
  float* score = bnorm + M;                       // B
  int* nnidx = (int*)(score + B);                 // B
  int* maxrow = nnidx + B;                        // B
  float* cvals = (float*)(maxrow + B);            // B*144
  int* cidx = (int*)(cvals + B * 144);            // B*144

  float* out_map = (float*)d_out;
  float* out_pred = out_map + (size_t)B * 224 * 224;

  const int total = (N + M) * (C / 8);
  prep_kernel<<<(total + 255) / 256, 256, 0, stream>>>(emb, bank, Abf, Bbf,
                                                       anorm, bnorm, packed,
                                                       N, M);
  nn_mfma<<<(N / 128) * 8, 256, 0, stream>>>(Abf, Bbf, bnorm, anorm, packed,
                                             N, M);
  batch_argmax<<<B, 256, 0, stream>>>(packed, score, nnidx, maxrow);
  rescore_part<<<dim3(16, B), 256, 0, stream>>>(bank, bnorm, nnidx, cvals,
                                                cidx, M);
  rescore_merge<<<B, 256, 0, stream>>>(emb, bank, cvals, cidx, score, maxrow,
                                       out_pred);
  blur_fused<<<dim3(224, B), 256, 0, stream>>>(packed, out_map);
}